// Round 11
// baseline (456.512 us; speedup 1.0000x reference)
//
#include <hip/hip_runtime.h>
#include <math.h>

typedef __attribute__((ext_vector_type(8))) short short8;
typedef __attribute__((ext_vector_type(4))) float f32x4;
typedef __attribute__((ext_vector_type(2))) unsigned int u32x2;
typedef __attribute__((ext_vector_type(4))) unsigned int u32x4;

#define E_NUM 16
constexpr int CAPS[E_NUM] = {1024,512,1024,256,1024,512,128,1024,512,1024,256,512,1024,128,64,512};
constexpr int OFFS[E_NUM] = {0,1024,1536,2560,2816,3840,4352,4480,5504,6016,7040,7296,7808,8832,8960,9024};
constexpr int cdiv_(int a, int b){ return (a + b - 1) / b; }
constexpr int ilog2_(int v){ int l = 0; while ((1 << l) < v) ++l; return l; }

__device__ __forceinline__ unsigned int cvt_pk_bf16(float a, float b){
  unsigned int r;
  asm("v_cvt_pk_bf16_f32 %0, %1, %2" : "=v"(r) : "v"(a), "v"(b));
  return r;
}

typedef __attribute__((address_space(1))) const unsigned char gas_u8;
typedef __attribute__((address_space(3))) unsigned char las_u8;
__device__ __forceinline__ void gl_lds16(const void* g, void* l){
  __builtin_amdgcn_global_load_lds((gas_u8*)g, (las_u8*)l, 16, 0, 0);
}

// x fp32 -> bf16 (RNE), 8 elems/thread, grid-stride
__global__ __launch_bounds__(256) void cvt_bf16_kernel(const float* __restrict__ x,
                                                       unsigned short* __restrict__ xb, int n8)
{
  int i = blockIdx.x * blockDim.x + threadIdx.x;
  const int stride = gridDim.x * blockDim.x;
  for (; i < n8; i += stride) {
    f32x4 a = *reinterpret_cast<const f32x4*>(x + (size_t)i * 8);
    f32x4 b = *reinterpret_cast<const f32x4*>(x + (size_t)i * 8 + 4);
    u32x2 lo, hi;
    lo[0] = cvt_pk_bf16(a[0], a[1]); lo[1] = cvt_pk_bf16(a[2], a[3]);
    hi[0] = cvt_pk_bf16(b[0], b[1]); hi[1] = cvt_pk_bf16(b[2], b[3]);
    *reinterpret_cast<u32x2*>(xb + (size_t)i * 8)     = lo;
    *reinterpret_cast<u32x2*>(xb + (size_t)i * 8 + 4) = hi;
  }
}

// ===================== G1: 256x256, 512 thr, 3-buf counted-vmcnt (proven) ===========
template<bool A_BF16, int NDIM, int KDIM, int LOG_GN, int NWG>
__global__ __launch_bounds__(512, 2)
void g1_gemm256(const void* __restrict__ Av, const float* __restrict__ W,
                const float* __restrict__ bias, void* __restrict__ Outv)
{
  constexpr int A_BYTES = 256 * 64;
  constexpr int B_BYTES = 256 * 128;
  constexpr int BUF  = A_BYTES + B_BYTES;   // 48 KB
  constexpr int NBUF = A_BF16 ? 3 : 2;
  constexpr int GN   = 1 << LOG_GN;
  constexpr int NTT  = KDIM / 32;
  static_assert(NWG % 8 == 0);
  static_assert(NTT >= 3);

  __shared__ __align__(16) char smem[NBUF * BUF];

  const int tid  = threadIdx.x;
  const int braw = blockIdx.x;
  const int tt = (braw & 7) * (NWG / 8) + (braw >> 3);

  int m0 = 0, n0 = 0, Me = 0, tok0 = 0;
  size_t wbase = 0, bbase = 0;
  {
    int acc0 = 0;
    #pragma unroll
    for (int i = 0; i < E_NUM; ++i) {
      const int mt  = cdiv_(CAPS[i], 256);
      const int lmt = ilog2_(mt);
      const int nb  = mt * (NDIM / 256);
      if (tt >= acc0 && tt < acc0 + nb) {
        const int loc = tt - acc0;
        const int g   = loc >> (lmt + LOG_GN);
        const int rem = loc & ((mt << LOG_GN) - 1);
        m0   = (rem >> LOG_GN) * 256;
        n0   = ((g << LOG_GN) | (rem & (GN - 1))) * 256;
        Me   = CAPS[i];
        tok0 = OFFS[i];
        wbase = (size_t)i * NDIM * KDIM;
        bbase = (size_t)i * NDIM;
      }
      acc0 += nb;
    }
  }
  const float* Wb = W + wbase;

  const int lane = tid & 63;
  const int wv   = tid >> 6;

  const unsigned short* Ah = (const unsigned short*)Av;
  const float*          Af = (const float*)Av;

  auto stageA = [&](int buf, int kt) {
    const unsigned short* Ag = Ah + (size_t)(tok0 + m0) * KDIM + kt * 32;
    char* dst0 = smem + buf * BUF;
    #pragma unroll
    for (int j = 0; j < 2; ++j) {
      const int rbase = j * 128 + wv * 16;
      const int r     = rbase + (lane >> 2);
      const int blk   = (lane & 3) ^ (r & 3);
      gl_lds16((const void*)(Ag + (size_t)r * KDIM + blk * 8), (void*)(dst0 + rbase * 64));
    }
  };
  auto stageB = [&](int buf, int kt) {
    const float* Bg = Wb + (size_t)n0 * KDIM + kt * 32;
    char* dst0 = smem + buf * BUF + A_BYTES;
    #pragma unroll
    for (int j = 0; j < 4; ++j) {
      const int rbase = j * 64 + wv * 8;
      const int r     = rbase + (lane >> 3);
      const int blk   = (lane & 7) ^ (r & 7);
      gl_lds16((const void*)(Bg + (size_t)r * KDIM + blk * 4), (void*)(dst0 + rbase * 128));
    }
  };

  // fallback A (fp32 reg-staged)
  const int fr = tid >> 1;
  const int fcq = (tid & 1) * 2;
  f32x4 raf[4];
  auto loadA_reg = [&](int kt) {
    const float* Ap = Af + (size_t)(tok0 + m0 + fr) * KDIM + kt * 32 + fcq * 8;
    #pragma unroll
    for (int i = 0; i < 4; ++i) raf[i] = *reinterpret_cast<const f32x4*>(Ap + i * 4);
  };
  auto writeA_reg = [&](int buf) {
    char* ab = smem + buf * BUF;
    #pragma unroll
    for (int i = 0; i < 2; ++i) {
      u32x2 p;
      p[0] = cvt_pk_bf16(raf[2*i][0], raf[2*i][1]);
      p[1] = cvt_pk_bf16(raf[2*i][2], raf[2*i][3]);
      const int blk = (fcq + i) ^ (fr & 3);
      *reinterpret_cast<u32x2*>(ab + fr * 64 + blk * 16) = p;
    }
  };

  const int wm   = (wv >> 2) * 128;
  const int wn   = (wv & 3) * 64;
  const int lrow = lane & 15;
  const int pa0  = (((lane >> 4) ^ (lane & 3)) << 4);
  const int pb0  = ((((lane >> 4) << 1) ^ (lane & 7)) << 4);

  f32x4 acc_[8][4];
  #pragma unroll
  for (int i = 0; i < 8; ++i)
    #pragma unroll
    for (int j = 0; j < 4; ++j)
      acc_[i][j] = (f32x4){0.f, 0.f, 0.f, 0.f};

  auto compute = [&](int cur) {
    const char* ab  = smem + cur * BUF;
    const char* bbp = smem + cur * BUF + A_BYTES;
    short8 bfr[4];
    #pragma unroll
    for (int f = 0; f < 4; ++f) {
      const char* rowp = bbp + (size_t)(wn + f * 16 + lrow) * 128;
      f32x4 lo = *reinterpret_cast<const f32x4*>(rowp + pb0);
      f32x4 hi = *reinterpret_cast<const f32x4*>(rowp + (pb0 ^ 16));
      u32x4 pk;
      pk[0] = cvt_pk_bf16(lo[0], lo[1]); pk[1] = cvt_pk_bf16(lo[2], lo[3]);
      pk[2] = cvt_pk_bf16(hi[0], hi[1]); pk[3] = cvt_pk_bf16(hi[2], hi[3]);
      bfr[f] = __builtin_bit_cast(short8, pk);
    }
    #pragma unroll
    for (int i = 0; i < 8; ++i) {
      short8 afr = *reinterpret_cast<const short8*>(ab + (wm + i * 16 + lrow) * 64 + pa0);
      #pragma unroll
      for (int j = 0; j < 4; ++j)
        acc_[i][j] = __builtin_amdgcn_mfma_f32_16x16x32_bf16(afr, bfr[j], acc_[i][j], 0, 0, 0);
    }
  };

  if constexpr (A_BF16) {
    stageA(0, 0); stageB(0, 0);
    stageA(1, 1); stageB(1, 1);
    int cur = 0, nx2 = 2;
    for (int kt = 0; kt < NTT; ++kt) {
      if (kt + 1 < NTT) asm volatile("s_waitcnt vmcnt(6)\n\ts_barrier" ::: "memory");
      else              asm volatile("s_waitcnt vmcnt(0)\n\ts_barrier" ::: "memory");
      __builtin_amdgcn_sched_barrier(0);
      if (kt + 2 < NTT) { stageA(nx2, kt + 2); stageB(nx2, kt + 2); }
      compute(cur);
      cur = (cur == 2) ? 0 : cur + 1;
      nx2 = (nx2 == 2) ? 0 : nx2 + 1;
    }
  } else {
    loadA_reg(0); stageB(0, 0); writeA_reg(0);
    __syncthreads();
    for (int kt = 0; kt < NTT; ++kt) {
      const int cur = kt & 1;
      if (kt + 1 < NTT) { stageB(cur ^ 1, kt + 1); loadA_reg(kt + 1); }
      compute(cur);
      if (kt + 1 < NTT) writeA_reg(cur ^ 1);
      __syncthreads();
    }
  }

  float bv[4];
  #pragma unroll
  for (int f = 0; f < 4; ++f)
    bv[f] = bias[bbase + n0 + wn + f * 16 + lrow];

  unsigned short* Oh = (unsigned short*)Outv;
  if constexpr (A_BF16) {
    __syncthreads();
    unsigned short* hout = (unsigned short*)smem;   // 128 KB
    #pragma unroll
    for (int i = 0; i < 8; ++i) {
      const int rbase = wm + i * 16 + (lane >> 4) * 4;
      #pragma unroll
      for (int j = 0; j < 4; ++j) {
        #pragma unroll
        for (int jj = 0; jj < 4; ++jj) {
          float xv = acc_[i][j][jj] + bv[j];
          float y2 = xv * (1.5957691216057308f + 0.07135481627f * xv * xv);
          float g  = xv * __builtin_amdgcn_rcpf(1.0f + __expf(-y2));
          hout[(rbase + jj) * 256 + wn + j * 16 + lrow] = (unsigned short)(cvt_pk_bf16(g, g) & 0xFFFFu);
        }
      }
    }
    __syncthreads();
    #pragma unroll
    for (int s = 0; s < 16; ++s) {
      const int row = s * 16 + (tid >> 5);
      const int c   = (tid & 31) * 8;
      if (m0 + row < Me) {
        *reinterpret_cast<short8*>(Oh + (size_t)(tok0 + m0 + row) * NDIM + n0 + c)
          = *reinterpret_cast<const short8*>(hout + row * 256 + c);
      }
    }
  } else {
    #pragma unroll
    for (int i = 0; i < 8; ++i) {
      const int rbase = wm + i * 16 + (lane >> 4) * 4;
      #pragma unroll
      for (int j = 0; j < 4; ++j) {
        #pragma unroll
        for (int jj = 0; jj < 4; ++jj) {
          int grow = m0 + rbase + jj;
          if (grow < Me) {
            float xv = acc_[i][j][jj] + bv[j];
            float y2 = xv * (1.5957691216057308f + 0.07135481627f * xv * xv);
            float g  = xv * __builtin_amdgcn_rcpf(1.0f + __expf(-y2));
            Oh[(size_t)(tok0 + grow) * NDIM + n0 + wn + j * 16 + lrow]
              = (unsigned short)(cvt_pk_bf16(g, g) & 0xFFFFu);
          }
        }
      }
    }
  }
}

// ========== G2: 256x256, 512 thr, KS=4, bf16-LDS, A-glds(3buf) + B-reg-3deep(2buf) =========
// LDS/iter = 128 KB (A glds-write 16 + B ds-write 16 + reads 96) vs 176 for fp32-B.
// Per iter VMEM issue = [loadB(t+3) x4, stageA(t+2) x2] = 6; barrier `vmcnt(6) lgkmcnt(0)`
// clears group t-2 = {B(t+1) regs, A(t) glds} exactly -> no extra waits anywhere.
// Swizzles (all at the b128 bank floor, verified):
//   A: phys_blk = blk ^ (r&3)        (write via pre-swizzled glds source, read pa0)
//   B: phys_blk = blk ^ ((r>>1)&3)   (ds_write + read pb0)
template<int NDIM, int KDIM, int NWG, int KS>
__global__ __launch_bounds__(512, 2)
void g2_gemm256(const unsigned short* __restrict__ Ah, const float* __restrict__ W,
                const float* __restrict__ bias, float* __restrict__ Of)
{
  constexpr int A_BYTES = 256 * 64;    // bf16 256x32
  constexpr int B_BYTES = 256 * 64;    // bf16 256x32
  constexpr int NT   = KDIM / (KS * 32);
  constexpr int NWG1 = NWG / KS;
  static_assert(NWG % 8 == 0);
  static_assert(NT >= 6 && (NT % 6 == 2), "loop is 6-phase unrolled + 2 tail iters");

  __shared__ __align__(16) char smem[3 * A_BYTES + 2 * B_BYTES];   // 80 KB
  char* abuf = smem;
  char* bbuf = smem + 3 * A_BYTES;

  const int tid  = threadIdx.x;
  const int braw = blockIdx.x;
  const int t = (braw & 7) * (NWG / 8) + (braw >> 3);
  const int kc    = t / NWG1;
  const int tt    = t % NWG1;
  const int kbase = kc * (KDIM / KS);

  // expert locate, 256-row m-tiles, m-fastest (1MB W2 n-panel stays L2-resident)
  int m0 = 0, n0 = 0, Me = 0, tok0 = 0;
  size_t wbase = 0, bbase = 0;
  {
    int acc0 = 0;
    #pragma unroll
    for (int i = 0; i < E_NUM; ++i) {
      const int mt = cdiv_(CAPS[i], 256);
      const int nb = mt * (NDIM / 256);
      if (tt >= acc0 && tt < acc0 + nb) {
        const int loc = tt - acc0;
        m0   = (loc & (mt - 1)) * 256;       // mt is pow2 for all caps
        n0   = (loc >> ilog2_(mt)) * 256;
        Me   = CAPS[i];
        tok0 = OFFS[i];
        wbase = (size_t)i * NDIM * KDIM;
        bbase = (size_t)i * NDIM;
      }
      acc0 += nb;
    }
  }
  const float* Wb = W + wbase;

  const int lane = tid & 63;
  const int wv   = tid >> 6;            // 0..7

  // ---- A: bf16 global -> LDS via gl_lds (2 instr/thread), src pre-swizzled ----
  auto stageA = [&](char* dst0, int kt) {
    const unsigned short* Ag = Ah + (size_t)(tok0 + m0) * KDIM + kbase + kt * 32;
    #pragma unroll
    for (int j = 0; j < 2; ++j) {
      const int rbase = wv * 32 + j * 16;
      const int r     = rbase + (lane >> 2);
      const int blk   = (lane & 3) ^ (r & 3);
      gl_lds16((const void*)(Ag + (size_t)r * KDIM + blk * 8), (void*)(dst0 + rbase * 64));
    }
  };

  // ---- B: fp32 -> regs (4 x f32x4 = 64B/thread), 3-deep ----
  const int br  = tid >> 1;             // 0..255 (row)
  const int bkh = (tid & 1) * 16;       // fp32 k offset
  auto loadB = [&](f32x4 (&R)[4], int kt) {
    const float* p = Wb + (size_t)(n0 + br) * KDIM + kbase + kt * 32 + bkh;
    #pragma unroll
    for (int i = 0; i < 4; ++i) R[i] = *reinterpret_cast<const f32x4*>(p + i * 4);
  };
  // write 32B bf16: logical blocks (tid&1)*2 + {0,1}; phys = blk ^ ((r>>1)&3)
  auto writeB = [&](char* dst0, f32x4 (&R)[4]) {
    const int s = (br >> 1) & 3;
    u32x4 q0, q1;
    q0[0] = cvt_pk_bf16(R[0][0], R[0][1]); q0[1] = cvt_pk_bf16(R[0][2], R[0][3]);
    q0[2] = cvt_pk_bf16(R[1][0], R[1][1]); q0[3] = cvt_pk_bf16(R[1][2], R[1][3]);
    q1[0] = cvt_pk_bf16(R[2][0], R[2][1]); q1[1] = cvt_pk_bf16(R[2][2], R[2][3]);
    q1[2] = cvt_pk_bf16(R[3][0], R[3][1]); q1[3] = cvt_pk_bf16(R[3][2], R[3][3]);
    const int b0 = (((tid & 1) * 2) + 0) ^ s;
    const int b1 = (((tid & 1) * 2) + 1) ^ s;
    *reinterpret_cast<u32x4*>(dst0 + br * 64 + b0 * 16) = q0;
    *reinterpret_cast<u32x4*>(dst0 + br * 64 + b1 * 16) = q1;
  };

  // ---- compute: wave-tile 128x64 (2M x 4N), 32 MFMA / 12 b128-reads per iter ----
  const int wm   = (wv >> 2) * 128;
  const int wn   = (wv & 3) * 64;
  const int lrow = lane & 15;
  const int pa0  = (((lane >> 4) ^ (lane & 3)) << 4);
  const int pb0  = (((lane >> 4) ^ ((lane >> 1) & 3)) << 4);

  f32x4 acc_[8][4];
  #pragma unroll
  for (int i = 0; i < 8; ++i)
    #pragma unroll
    for (int j = 0; j < 4; ++j)
      acc_[i][j] = (f32x4){0.f, 0.f, 0.f, 0.f};

  auto compute = [&](const char* ab, const char* bb) {
    short8 bfr[4];
    #pragma unroll
    for (int f = 0; f < 4; ++f)
      bfr[f] = *reinterpret_cast<const short8*>(bb + (wn + f * 16 + lrow) * 64 + pb0);
    #pragma unroll
    for (int i = 0; i < 8; ++i) {
      short8 afr = *reinterpret_cast<const short8*>(ab + (wm + i * 16 + lrow) * 64 + pa0);
      #pragma unroll
      for (int j = 0; j < 4; ++j)
        acc_[i][j] = __builtin_amdgcn_mfma_f32_16x16x32_bf16(afr, bfr[j], acc_[i][j], 0, 0, 0);
    }
  };

  // ---- prologue: B0,B1 regs; A0,A1 glds; B2 regs; write B0 to LDS ----
  f32x4 Br0[4], Br1[4], Br2[4];
  loadB(Br0, 0); loadB(Br1, 1);                       // 8 vmem
  stageA(abuf + 0 * A_BYTES, 0);                      // +2
  stageA(abuf + 1 * A_BYTES, 1);                      // +2
  loadB(Br2, 2);                                      // +4  (16 total)
  asm volatile("s_waitcnt vmcnt(12)" ::: "memory");   // Br0 complete
  writeB(bbuf + 0 * B_BYTES, Br0);

  // ---- 6-phase unrolled main loop (static Br / buffer indices, rule #20) ----
#define G2_ITER(T, AC, AS, BC, BW, BRW, BRL)                                        \
  { const int t_ = (T);                                                             \
    if (t_ + 3 <= NT) { asm volatile("s_waitcnt vmcnt(6) lgkmcnt(0)\n\ts_barrier" ::: "memory"); } \
    else              { asm volatile("s_waitcnt vmcnt(0) lgkmcnt(0)\n\ts_barrier" ::: "memory"); } \
    __builtin_amdgcn_sched_barrier(0);                                              \
    if (t_ + 1 < NT) writeB(bbuf + (BW) * B_BYTES, BRW);                            \
    if (t_ + 3 < NT) loadB(BRL, t_ + 3);                                            \
    if (t_ + 2 < NT) stageA(abuf + (AS) * A_BYTES, t_ + 2);                         \
    compute(abuf + (AC) * A_BYTES, bbuf + (BC) * B_BYTES); }

  for (int tb = 0; tb < NT - 2; tb += 6) {
    G2_ITER(tb + 0, 0, 2, 0, 1, Br1, Br0)
    G2_ITER(tb + 1, 1, 0, 1, 0, Br2, Br1)
    G2_ITER(tb + 2, 2, 1, 0, 1, Br0, Br2)
    G2_ITER(tb + 3, 0, 2, 1, 0, Br1, Br0)
    G2_ITER(tb + 4, 1, 0, 0, 1, Br2, Br1)
    G2_ITER(tb + 5, 2, 1, 1, 0, Br0, Br2)
  }
  G2_ITER(NT - 2, 0, 2, 0, 1, Br1, Br0)   // NT%6==2: tail phases 0,1
  G2_ITER(NT - 1, 1, 0, 1, 0, Br2, Br1)
#undef G2_ITER

  // ---- epilogue: split-K atomic accumulate, bias/KS folded ----
  float bv[4];
  #pragma unroll
  for (int f = 0; f < 4; ++f)
    bv[f] = bias[bbase + n0 + wn + f * 16 + lrow];

  constexpr float BS = 1.0f / (float)KS;
  #pragma unroll
  for (int i = 0; i < 8; ++i) {
    const int rbase = wm + i * 16 + (lane >> 4) * 4;
    #pragma unroll
    for (int jj = 0; jj < 4; ++jj) {
      int grow = m0 + rbase + jj;
      if (grow < Me) {
        #pragma unroll
        for (int j = 0; j < 4; ++j) {
          float v = acc_[i][j][jj] + bv[j] * BS;
          unsafeAtomicAdd(Of + (size_t)(tok0 + grow) * NDIM + n0 + wn + j * 16 + lrow, v);
        }
      }
    }
  }
}

extern "C" void kernel_launch(void* const* d_in, const int* in_sizes, int n_in,
                              void* d_out, int out_size, void* d_ws, size_t ws_size,
                              hipStream_t stream)
{
  const float* x  = (const float*)d_in[0];
  const float* W1 = (const float*)d_in[1];
  const float* b1 = (const float*)d_in[2];
  const float* W2 = (const float*)d_in[3];
  const float* b2 = (const float*)d_in[4];
  float* out = (float*)d_out;

  constexpr size_t H_BYTES  = (size_t)9536 * 4096 * 2;
  constexpr size_t XB_BYTES = (size_t)9536 * 1024 * 2;
  unsigned short* h  = (unsigned short*)d_ws;
  unsigned short* xb = (unsigned short*)((char*)d_ws + H_BYTES);

  const bool use_xb = ws_size >= H_BYTES + XB_BYTES;

  // zero d_out for split-K atomic accumulation
  hipMemsetAsync(d_out, 0, (size_t)out_size * sizeof(float), stream);

  // G1: 39 m-tiles(256) x 16 n-tiles = 624 blocks
  if (use_xb) {
    cvt_bf16_kernel<<<2048, 256, 0, stream>>>(x, xb, 9536 * 1024 / 8);
    g1_gemm256<true, 4096, 1024, 2, 624>
        <<<624, 512, 0, stream>>>((const void*)xb, W1, b1, (void*)h);
  } else {
    g1_gemm256<false, 4096, 1024, 2, 624>
        <<<624, 512, 0, stream>>>((const void*)x, W1, b1, (void*)h);
  }

  // G2: 39 m-tiles(256) x 4 n-tiles x KS4 = 624 blocks; NT = 4096/(4*32) = 32
  g2_gemm256<1024, 4096, 624, 4>
      <<<624, 512, 0, stream>>>(h, W2, b2, out);
}

// Round 12
// 358.061 us; speedup vs baseline: 1.2750x; 1.2750x over previous
//
#include <hip/hip_runtime.h>
#include <math.h>

typedef __attribute__((ext_vector_type(8))) short short8;
typedef __attribute__((ext_vector_type(4))) float f32x4;
typedef __attribute__((ext_vector_type(2))) unsigned int u32x2;
typedef __attribute__((ext_vector_type(4))) unsigned int u32x4;

#define E_NUM 16
constexpr int CAPS[E_NUM] = {1024,512,1024,256,1024,512,128,1024,512,1024,256,512,1024,128,64,512};
constexpr int OFFS[E_NUM] = {0,1024,1536,2560,2816,3840,4352,4480,5504,6016,7040,7296,7808,8832,8960,9024};
constexpr int cdiv_(int a, int b){ return (a + b - 1) / b; }
constexpr int ilog2_(int v){ int l = 0; while ((1 << l) < v) ++l; return l; }

__device__ __forceinline__ unsigned int cvt_pk_bf16(float a, float b){
  unsigned int r;
  asm("v_cvt_pk_bf16_f32 %0, %1, %2" : "=v"(r) : "v"(a), "v"(b));
  return r;
}

typedef __attribute__((address_space(1))) const unsigned char gas_u8;
typedef __attribute__((address_space(3))) unsigned char las_u8;
__device__ __forceinline__ void gl_lds16(const void* g, void* l){
  __builtin_amdgcn_global_load_lds((gas_u8*)g, (las_u8*)l, 16, 0, 0);
}

// x fp32 -> bf16 (RNE), 8 elems/thread, grid-stride
__global__ __launch_bounds__(256) void cvt_bf16_kernel(const float* __restrict__ x,
                                                       unsigned short* __restrict__ xb, int n8)
{
  int i = blockIdx.x * blockDim.x + threadIdx.x;
  const int stride = gridDim.x * blockDim.x;
  for (; i < n8; i += stride) {
    f32x4 a = *reinterpret_cast<const f32x4*>(x + (size_t)i * 8);
    f32x4 b = *reinterpret_cast<const f32x4*>(x + (size_t)i * 8 + 4);
    u32x2 lo, hi;
    lo[0] = cvt_pk_bf16(a[0], a[1]); lo[1] = cvt_pk_bf16(a[2], a[3]);
    hi[0] = cvt_pk_bf16(b[0], b[1]); hi[1] = cvt_pk_bf16(b[2], b[3]);
    *reinterpret_cast<u32x2*>(xb + (size_t)i * 8)     = lo;
    *reinterpret_cast<u32x2*>(xb + (size_t)i * 8 + 4) = hi;
  }
}

// ===================== G1: 256x256, 512 thr, 3-buf counted-vmcnt (proven ~145us) =====
template<bool A_BF16, int NDIM, int KDIM, int LOG_GN, int NWG>
__global__ __launch_bounds__(512, 2)
void g1_gemm256(const void* __restrict__ Av, const float* __restrict__ W,
                const float* __restrict__ bias, void* __restrict__ Outv)
{
  constexpr int A_BYTES = 256 * 64;
  constexpr int B_BYTES = 256 * 128;
  constexpr int BUF  = A_BYTES + B_BYTES;   // 48 KB
  constexpr int NBUF = A_BF16 ? 3 : 2;
  constexpr int GN   = 1 << LOG_GN;
  constexpr int NTT  = KDIM / 32;
  static_assert(NWG % 8 == 0);
  static_assert(NTT >= 3);

  __shared__ __align__(16) char smem[NBUF * BUF];

  const int tid  = threadIdx.x;
  const int braw = blockIdx.x;
  const int tt = (braw & 7) * (NWG / 8) + (braw >> 3);

  int m0 = 0, n0 = 0, Me = 0, tok0 = 0;
  size_t wbase = 0, bbase = 0;
  {
    int acc0 = 0;
    #pragma unroll
    for (int i = 0; i < E_NUM; ++i) {
      const int mt  = cdiv_(CAPS[i], 256);
      const int lmt = ilog2_(mt);
      const int nb  = mt * (NDIM / 256);
      if (tt >= acc0 && tt < acc0 + nb) {
        const int loc = tt - acc0;
        const int g   = loc >> (lmt + LOG_GN);
        const int rem = loc & ((mt << LOG_GN) - 1);
        m0   = (rem >> LOG_GN) * 256;
        n0   = ((g << LOG_GN) | (rem & (GN - 1))) * 256;
        Me   = CAPS[i];
        tok0 = OFFS[i];
        wbase = (size_t)i * NDIM * KDIM;
        bbase = (size_t)i * NDIM;
      }
      acc0 += nb;
    }
  }
  const float* Wb = W + wbase;

  const int lane = tid & 63;
  const int wv   = tid >> 6;

  const unsigned short* Ah = (const unsigned short*)Av;
  const float*          Af = (const float*)Av;

  auto stageA = [&](int buf, int kt) {
    const unsigned short* Ag = Ah + (size_t)(tok0 + m0) * KDIM + kt * 32;
    char* dst0 = smem + buf * BUF;
    #pragma unroll
    for (int j = 0; j < 2; ++j) {
      const int rbase = j * 128 + wv * 16;
      const int r     = rbase + (lane >> 2);
      const int blk   = (lane & 3) ^ (r & 3);
      gl_lds16((const void*)(Ag + (size_t)r * KDIM + blk * 8), (void*)(dst0 + rbase * 64));
    }
  };
  auto stageB = [&](int buf, int kt) {
    const float* Bg = Wb + (size_t)n0 * KDIM + kt * 32;
    char* dst0 = smem + buf * BUF + A_BYTES;
    #pragma unroll
    for (int j = 0; j < 4; ++j) {
      const int rbase = j * 64 + wv * 8;
      const int r     = rbase + (lane >> 3);
      const int blk   = (lane & 7) ^ (r & 7);
      gl_lds16((const void*)(Bg + (size_t)r * KDIM + blk * 4), (void*)(dst0 + rbase * 128));
    }
  };

  // fallback A (fp32 reg-staged)
  const int fr = tid >> 1;
  const int fcq = (tid & 1) * 2;
  f32x4 raf[4];
  auto loadA_reg = [&](int kt) {
    const float* Ap = Af + (size_t)(tok0 + m0 + fr) * KDIM + kt * 32 + fcq * 8;
    #pragma unroll
    for (int i = 0; i < 4; ++i) raf[i] = *reinterpret_cast<const f32x4*>(Ap + i * 4);
  };
  auto writeA_reg = [&](int buf) {
    char* ab = smem + buf * BUF;
    #pragma unroll
    for (int i = 0; i < 2; ++i) {
      u32x2 p;
      p[0] = cvt_pk_bf16(raf[2*i][0], raf[2*i][1]);
      p[1] = cvt_pk_bf16(raf[2*i][2], raf[2*i][3]);
      const int blk = (fcq + i) ^ (fr & 3);
      *reinterpret_cast<u32x2*>(ab + fr * 64 + blk * 16) = p;
    }
  };

  const int wm   = (wv >> 2) * 128;
  const int wn   = (wv & 3) * 64;
  const int lrow = lane & 15;
  const int pa0  = (((lane >> 4) ^ (lane & 3)) << 4);
  const int pb0  = ((((lane >> 4) << 1) ^ (lane & 7)) << 4);

  f32x4 acc_[8][4];
  #pragma unroll
  for (int i = 0; i < 8; ++i)
    #pragma unroll
    for (int j = 0; j < 4; ++j)
      acc_[i][j] = (f32x4){0.f, 0.f, 0.f, 0.f};

  auto compute = [&](int cur) {
    const char* ab  = smem + cur * BUF;
    const char* bbp = smem + cur * BUF + A_BYTES;
    short8 bfr[4];
    #pragma unroll
    for (int f = 0; f < 4; ++f) {
      const char* rowp = bbp + (size_t)(wn + f * 16 + lrow) * 128;
      f32x4 lo = *reinterpret_cast<const f32x4*>(rowp + pb0);
      f32x4 hi = *reinterpret_cast<const f32x4*>(rowp + (pb0 ^ 16));
      u32x4 pk;
      pk[0] = cvt_pk_bf16(lo[0], lo[1]); pk[1] = cvt_pk_bf16(lo[2], lo[3]);
      pk[2] = cvt_pk_bf16(hi[0], hi[1]); pk[3] = cvt_pk_bf16(hi[2], hi[3]);
      bfr[f] = __builtin_bit_cast(short8, pk);
    }
    #pragma unroll
    for (int i = 0; i < 8; ++i) {
      short8 afr = *reinterpret_cast<const short8*>(ab + (wm + i * 16 + lrow) * 64 + pa0);
      #pragma unroll
      for (int j = 0; j < 4; ++j)
        acc_[i][j] = __builtin_amdgcn_mfma_f32_16x16x32_bf16(afr, bfr[j], acc_[i][j], 0, 0, 0);
    }
  };

  if constexpr (A_BF16) {
    stageA(0, 0); stageB(0, 0);
    stageA(1, 1); stageB(1, 1);
    int cur = 0, nx2 = 2;
    for (int kt = 0; kt < NTT; ++kt) {
      if (kt + 1 < NTT) asm volatile("s_waitcnt vmcnt(6)\n\ts_barrier" ::: "memory");
      else              asm volatile("s_waitcnt vmcnt(0)\n\ts_barrier" ::: "memory");
      __builtin_amdgcn_sched_barrier(0);
      if (kt + 2 < NTT) { stageA(nx2, kt + 2); stageB(nx2, kt + 2); }
      compute(cur);
      cur = (cur == 2) ? 0 : cur + 1;
      nx2 = (nx2 == 2) ? 0 : nx2 + 1;
    }
  } else {
    loadA_reg(0); stageB(0, 0); writeA_reg(0);
    __syncthreads();
    for (int kt = 0; kt < NTT; ++kt) {
      const int cur = kt & 1;
      if (kt + 1 < NTT) { stageB(cur ^ 1, kt + 1); loadA_reg(kt + 1); }
      compute(cur);
      if (kt + 1 < NTT) writeA_reg(cur ^ 1);
      __syncthreads();
    }
  }

  float bv[4];
  #pragma unroll
  for (int f = 0; f < 4; ++f)
    bv[f] = bias[bbase + n0 + wn + f * 16 + lrow];

  unsigned short* Oh = (unsigned short*)Outv;
  if constexpr (A_BF16) {
    __syncthreads();
    unsigned short* hout = (unsigned short*)smem;   // 128 KB
    #pragma unroll
    for (int i = 0; i < 8; ++i) {
      const int rbase = wm + i * 16 + (lane >> 4) * 4;
      #pragma unroll
      for (int j = 0; j < 4; ++j) {
        #pragma unroll
        for (int jj = 0; jj < 4; ++jj) {
          float xv = acc_[i][j][jj] + bv[j];
          float y2 = xv * (1.5957691216057308f + 0.07135481627f * xv * xv);
          float g  = xv * __builtin_amdgcn_rcpf(1.0f + __expf(-y2));
          hout[(rbase + jj) * 256 + wn + j * 16 + lrow] = (unsigned short)(cvt_pk_bf16(g, g) & 0xFFFFu);
        }
      }
    }
    __syncthreads();
    #pragma unroll
    for (int s = 0; s < 16; ++s) {
      const int row = s * 16 + (tid >> 5);
      const int c   = (tid & 31) * 8;
      if (m0 + row < Me) {
        *reinterpret_cast<short8*>(Oh + (size_t)(tok0 + m0 + row) * NDIM + n0 + c)
          = *reinterpret_cast<const short8*>(hout + row * 256 + c);
      }
    }
  } else {
    #pragma unroll
    for (int i = 0; i < 8; ++i) {
      const int rbase = wm + i * 16 + (lane >> 4) * 4;
      #pragma unroll
      for (int j = 0; j < 4; ++j) {
        #pragma unroll
        for (int jj = 0; jj < 4; ++jj) {
          int grow = m0 + rbase + jj;
          if (grow < Me) {
            float xv = acc_[i][j][jj] + bv[j];
            float y2 = xv * (1.5957691216057308f + 0.07135481627f * xv * xv);
            float g  = xv * __builtin_amdgcn_rcpf(1.0f + __expf(-y2));
            Oh[(size_t)(tok0 + grow) * NDIM + n0 + wn + j * 16 + lrow]
              = (unsigned short)(cvt_pk_bf16(g, g) & 0xFFFFu);
          }
        }
      }
    }
  }
}

// ====== G2: 128x128, 256 thr, 2-barrier, A-glds + B-reg-staged bf16 (R6-proven) ======
// GN=1 (LOG_GN=0): all m-tiles of an expert walk one 128-col W2 n-panel (2 MB,
// L2-resident per XCD) before advancing n -> loadB is an L2 hit (~200cy not ~900cy).
// 32 KB LDS -> ~5 blocks/CU, ~20 waves/CU: cross-block TLP covers the barrier drain.
template<int NDIM, int KDIM, int LOG_GN, int NWG, int KS>
__global__ __launch_bounds__(256, 8)
void g2_gemm128(const unsigned short* __restrict__ Ah, const float* __restrict__ W,
                const float* __restrict__ bias, float* __restrict__ Of)
{
  constexpr int A_BYTES = 128 * 64;
  constexpr int B_BYTES = 128 * 64;
  constexpr int GN   = 1 << LOG_GN;
  constexpr int NT   = KDIM / (KS * 32);
  constexpr int NWG1 = NWG / KS;
  static_assert(NWG % 8 == 0);

  __shared__ __align__(16) char smem[2 * A_BYTES + 2 * B_BYTES];   // 32 KB

  const int tid  = threadIdx.x;
  const int braw = blockIdx.x;
  const int t = (braw & 7) * (NWG / 8) + (braw >> 3);

  const int kc    = t / NWG1;           // chunk-major: XCDs 0-3 chunk0, 4-7 chunk1
  const int tt    = t % NWG1;
  const int kbase = kc * (KDIM / KS);

  int m0 = 0, n0 = 0, Me = 0, tok0 = 0;
  size_t wbase = 0, bbase = 0;
  {
    int acc0 = 0;
    #pragma unroll
    for (int i = 0; i < E_NUM; ++i) {
      const int mt  = cdiv_(CAPS[i], 128);
      const int lmt = ilog2_(mt);
      const int nb  = mt * (NDIM / 128);
      if (tt >= acc0 && tt < acc0 + nb) {
        const int loc = tt - acc0;
        const int g   = loc >> (lmt + LOG_GN);
        const int rem = loc & ((mt << LOG_GN) - 1);
        m0   = (rem >> LOG_GN) * 128;
        n0   = ((g << LOG_GN) | (rem & (GN - 1))) * 128;
        Me   = CAPS[i];
        tok0 = OFFS[i];
        wbase = (size_t)i * NDIM * KDIM;
        bbase = (size_t)i * NDIM;
      }
      acc0 += nb;
    }
  }
  const float* Wb = W + wbase;

  const int lane = tid & 63;
  const int wv   = tid >> 6;
  const int sr   = tid >> 3;
  const int sc   = (tid & 7) * 8;                  // byte col
  const int spc  = sc ^ (((sr >> 2) & 3) << 4);

  f32x4 rb[4];
  auto loadB = [&](int kt) {
    const int k0 = kbase + kt * 32;
    #pragma unroll
    for (int i = 0; i < 4; ++i)
      rb[i] = *reinterpret_cast<const f32x4*>(Wb + (size_t)(n0 + sr + 32 * i) * KDIM + k0 + (sc >> 1));
  };
  auto writeB = [&](int buf) {
    char* bb = smem + 2 * A_BYTES + buf * B_BYTES;
    #pragma unroll
    for (int i = 0; i < 4; ++i) {
      u32x2 p;
      p[0] = cvt_pk_bf16(rb[i][0], rb[i][1]);
      p[1] = cvt_pk_bf16(rb[i][2], rb[i][3]);
      *reinterpret_cast<u32x2*>(bb + (sr + 32 * i) * 64 + spc) = p;
    }
  };

  auto stageA = [&](int buf, int kt) {
    const unsigned short* Ag = Ah + (size_t)(tok0 + m0) * KDIM + kbase + kt * 32;
    char* dst0 = smem + buf * A_BYTES;
    #pragma unroll
    for (int j = 0; j < 2; ++j) {
      const int rbase = wv * 32 + j * 16;
      const int r     = rbase + (lane >> 2);
      const int blk   = (lane & 3) ^ ((r >> 2) & 3);
      gl_lds16((const void*)(Ag + (size_t)r * KDIM + blk * 8), (void*)(dst0 + rbase * 64));
    }
  };

  const int wm   = (wv >> 1) * 64;
  const int wn   = (wv & 1) * 64;
  const int lrow = lane & 15;
  const int fcs  = ((lane >> 4) << 4) ^ (((lane >> 2) & 3) << 4);

  f32x4 acc_[4][4];
  #pragma unroll
  for (int i = 0; i < 4; ++i)
    #pragma unroll
    for (int j = 0; j < 4; ++j)
      acc_[i][j] = (f32x4){0.f, 0.f, 0.f, 0.f};

  auto mfma_step = [&](int cur) {
    const char* ab = smem + cur * A_BYTES;
    const char* bb = smem + 2 * A_BYTES + cur * B_BYTES;
    short8 afr[4], bfr[4];
    #pragma unroll
    for (int f = 0; f < 4; ++f)
      afr[f] = *reinterpret_cast<const short8*>(ab + (wm + f * 16 + lrow) * 64 + fcs);
    #pragma unroll
    for (int f = 0; f < 4; ++f)
      bfr[f] = *reinterpret_cast<const short8*>(bb + (wn + f * 16 + lrow) * 64 + fcs);
    #pragma unroll
    for (int i = 0; i < 4; ++i)
      #pragma unroll
      for (int j = 0; j < 4; ++j)
        acc_[i][j] = __builtin_amdgcn_mfma_f32_16x16x32_bf16(afr[i], bfr[j], acc_[i][j], 0, 0, 0);
  };

  loadB(0); stageA(0, 0); writeB(0);
  __syncthreads();

  for (int kt = 0; kt < NT; ++kt) {
    const int cur = kt & 1;
    if (kt + 1 < NT) { loadB(kt + 1); stageA(cur ^ 1, kt + 1); }
    mfma_step(cur);
    if (kt + 1 < NT) writeB(cur ^ 1);
    __syncthreads();
  }

  float bv[4];
  #pragma unroll
  for (int f = 0; f < 4; ++f)
    bv[f] = bias[bbase + n0 + wn + f * 16 + lrow];

  constexpr float BS = 1.0f / (float)KS;
  #pragma unroll
  for (int i = 0; i < 4; ++i) {
    const int rbase = wm + i * 16 + (lane >> 4) * 4;
    #pragma unroll
    for (int jj = 0; jj < 4; ++jj) {
      int grow = m0 + rbase + jj;
      if (grow < Me) {
        #pragma unroll
        for (int j = 0; j < 4; ++j) {
          float v = acc_[i][j][jj] + bv[j] * BS;
          float* p = Of + (size_t)(tok0 + grow) * NDIM + n0 + wn + j * 16 + lrow;
          if constexpr (KS > 1) unsafeAtomicAdd(p, v);
          else                  *p = v;
        }
      }
    }
  }
}

extern "C" void kernel_launch(void* const* d_in, const int* in_sizes, int n_in,
                              void* d_out, int out_size, void* d_ws, size_t ws_size,
                              hipStream_t stream)
{
  const float* x  = (const float*)d_in[0];
  const float* W1 = (const float*)d_in[1];
  const float* b1 = (const float*)d_in[2];
  const float* W2 = (const float*)d_in[3];
  const float* b2 = (const float*)d_in[4];
  float* out = (float*)d_out;

  constexpr size_t H_BYTES  = (size_t)9536 * 4096 * 2;
  constexpr size_t XB_BYTES = (size_t)9536 * 1024 * 2;
  unsigned short* h  = (unsigned short*)d_ws;
  unsigned short* xb = (unsigned short*)((char*)d_ws + H_BYTES);

  const bool use_xb = ws_size >= H_BYTES + XB_BYTES;

  // zero d_out for split-K atomic accumulation
  hipMemsetAsync(d_out, 0, (size_t)out_size * sizeof(float), stream);

  // G1: 39 m-tiles(256) x 16 n-tiles = 624 blocks
  if (use_xb) {
    cvt_bf16_kernel<<<2048, 256, 0, stream>>>(x, xb, 9536 * 1024 / 8);
    g1_gemm256<true, 4096, 1024, 2, 624>
        <<<624, 512, 0, stream>>>((const void*)xb, W1, b1, (void*)h);
  } else {
    g1_gemm256<false, 4096, 1024, 2, 624>
        <<<624, 512, 0, stream>>>((const void*)x, W1, b1, (void*)h);
  }

  // G2: 75 m-tiles(128) x 8 n-tiles x KS2 = 1200 blocks, GN=1 (W2 panel L2-resident)
  g2_gemm128<1024, 4096, 0, 1200, 2>
      <<<1200, 256, 0, stream>>>(h, W2, b2, out);
}